// Round 1
// baseline (103.516 us; speedup 1.0000x reference)
//
#include <hip/hip_runtime.h>
#include <math.h>

#define Bn   2
#define En   2048
#define N1n  96
#define Kn   32
#define CINn 64
#define CBn  32
#define On   64
#define Gn   4
#define Fn   160   // 2*CIN + CB
#define NEG  0.01f

// ---------------------------------------------------------------------------
// Kernel 1: Weff[k][f][o] = (1/G) * sum_g w_g(k) * W_eq[g][f][o]
//   w_g(k) = [ perms1[g, inv2[g,k]] == k ],  inv2 = argsort(perms2, axis=1)
// (with perms1==perms2 this is identically 1, but we compute it for generality)
// ---------------------------------------------------------------------------
__global__ void weff_kernel(const float* __restrict__ W_eq,
                            const int* __restrict__ perms1,
                            const int* __restrict__ perms2,
                            float* __restrict__ Weff) {
    const int FO = Fn * On;
    int idx = blockIdx.x * blockDim.x + threadIdx.x;
    if (idx >= Kn * FO) return;
    int k = idx / FO;
    int r = idx - k * FO;
    float s = 0.f;
#pragma unroll
    for (int g = 0; g < Gn; ++g) {
        int j = 0;
        for (; j < Kn; ++j) if (perms2[g * Kn + j] == k) break;
        float wg = (j < Kn && perms1[g * Kn + j] == k) ? 1.f : 0.f;
        s += wg * W_eq[g * FO + r];
    }
    Weff[idx] = 0.25f * s;
}

// ---------------------------------------------------------------------------
// Kernel 2: one wave (64 threads) per (b,e) edge.
//   v[0:160] = [sites1[b,idx1[e]], sites2[b,idx2[e]], bonds[b,e]]  (LDS)
//   lane t: og = t&15 (output quad o=4*og..4*og+3), fg = t>>4 (f stripe)
//   acc4 = sum_{f ≡ fg mod 4} v[f] * W[k2][f][4og..4og+3]   (float4 loads)
//   xor-shuffle(16,32) reduces the 4 f-stripes; leaky-relu + bias;
//   att = sigmoid(dot(lat, W_att)+b_att) via xor-shuffle(1,2,4,8);
//   lanes fg==0 atomicAdd att*lat into out[b, k2, :].
// ---------------------------------------------------------------------------
template <bool USE_WEFF>
__global__ void __launch_bounds__(64)
edge_kernel(const float* __restrict__ sites1, const float* __restrict__ sites2,
            const float* __restrict__ bonds,  const float* __restrict__ W,
            const float* __restrict__ b_eq,   const float* __restrict__ W_att,
            const float* __restrict__ b_att,  const int* __restrict__ idx1,
            const int* __restrict__ idx2,     const int* __restrict__ perms1,
            const int* __restrict__ perms2,   float* __restrict__ out) {
    const int t  = threadIdx.x;        // 0..63
    const int be = blockIdx.x;         // 0..B*E-1
    const int b  = be >> 11;           // E = 2048
    const int e  = be & (En - 1);

    __shared__ float v[Fn];
    __shared__ float wgs[Gn];

    const int i1 = idx1[e];
    const int k2 = idx2[e];

    v[t]        = sites1[(b * N1n + i1) * CINn + t];
    v[CINn + t] = sites2[(b * Kn  + k2) * CINn + t];
    if (t < CBn) v[2 * CINn + t] = bonds[(b * En + e) * CBn + t];

    if (!USE_WEFF && t < Gn) {
        int g = t, j = 0;
        for (; j < Kn; ++j) if (perms2[g * Kn + j] == k2) break;
        wgs[g] = (j < Kn && perms1[g * Kn + j] == k2) ? 1.f : 0.f;
    }
    __syncthreads();

    const int og = t & 15;
    const int fg = t >> 4;

    float4 acc = make_float4(0.f, 0.f, 0.f, 0.f);
    if (USE_WEFF) {
        const float4* Wk = (const float4*)(W + (size_t)k2 * Fn * On);
#pragma unroll 4
        for (int f = fg; f < Fn; f += 4) {
            float  vf = v[f];
            float4 w  = Wk[f * 16 + og];
            acc.x += vf * w.x; acc.y += vf * w.y;
            acc.z += vf * w.z; acc.w += vf * w.w;
        }
    } else {
        const float w0 = wgs[0], w1 = wgs[1], w2 = wgs[2], w3 = wgs[3];
        const float4* W4 = (const float4*)W;
#pragma unroll 2
        for (int f = fg; f < Fn; f += 4) {
            float  vf = 0.25f * v[f];
            float4 a0 = W4[(0 * Fn + f) * 16 + og];
            float4 a1 = W4[(1 * Fn + f) * 16 + og];
            float4 a2 = W4[(2 * Fn + f) * 16 + og];
            float4 a3 = W4[(3 * Fn + f) * 16 + og];
            acc.x += vf * (w0 * a0.x + w1 * a1.x + w2 * a2.x + w3 * a3.x);
            acc.y += vf * (w0 * a0.y + w1 * a1.y + w2 * a2.y + w3 * a3.y);
            acc.z += vf * (w0 * a0.z + w1 * a1.z + w2 * a2.z + w3 * a3.z);
            acc.w += vf * (w0 * a0.w + w1 * a1.w + w2 * a2.w + w3 * a3.w);
        }
    }

    // reduce over the 4 f-stripes (lanes differing in bits 4,5)
#pragma unroll
    for (int m = 16; m <= 32; m <<= 1) {
        acc.x += __shfl_xor(acc.x, m);
        acc.y += __shfl_xor(acc.y, m);
        acc.z += __shfl_xor(acc.z, m);
        acc.w += __shfl_xor(acc.w, m);
    }

    const float4 be4 = ((const float4*)b_eq)[og];
    float4 lat;
    lat.x = acc.x + be4.x; lat.x = lat.x > 0.f ? lat.x : NEG * lat.x;
    lat.y = acc.y + be4.y; lat.y = lat.y > 0.f ? lat.y : NEG * lat.y;
    lat.z = acc.z + be4.z; lat.z = lat.z > 0.f ? lat.z : NEG * lat.z;
    lat.w = acc.w + be4.w; lat.w = lat.w > 0.f ? lat.w : NEG * lat.w;

    // attention dot product over o (16 lanes per stripe cover all 64 o's)
    const float4 wa = ((const float4*)W_att)[og];
    float part = lat.x * wa.x + lat.y * wa.y + lat.z * wa.z + lat.w * wa.w;
#pragma unroll
    for (int m = 1; m <= 8; m <<= 1) part += __shfl_xor(part, m);

    const float att = 1.f / (1.f + expf(-(part + b_att[0])));

    if (fg == 0) {
        float* op = out + ((size_t)b * Kn + k2) * On + og * 4;
        atomicAdd(op + 0, att * lat.x);
        atomicAdd(op + 1, att * lat.y);
        atomicAdd(op + 2, att * lat.z);
        atomicAdd(op + 3, att * lat.w);
    }
}

// ---------------------------------------------------------------------------
extern "C" void kernel_launch(void* const* d_in, const int* in_sizes, int n_in,
                              void* d_out, int out_size, void* d_ws, size_t ws_size,
                              hipStream_t stream) {
    const float* sites1 = (const float*)d_in[0];
    const float* sites2 = (const float*)d_in[1];
    const float* bonds  = (const float*)d_in[2];
    const float* W_eq   = (const float*)d_in[3];
    const float* b_eq   = (const float*)d_in[4];
    const float* W_att  = (const float*)d_in[5];
    const float* b_att  = (const float*)d_in[6];
    /* d_in[7] = idx2_oh (unused — reduced algebraically) */
    const int*   idx1   = (const int*)d_in[8];
    const int*   idx2   = (const int*)d_in[9];
    const int*   perms1 = (const int*)d_in[10];
    const int*   perms2 = (const int*)d_in[11];
    float* out = (float*)d_out;

    hipMemsetAsync(out, 0, (size_t)out_size * sizeof(float), stream);

    const size_t weff_bytes = (size_t)Kn * Fn * On * sizeof(float);
    if (ws_size >= weff_bytes) {
        float* Weff = (float*)d_ws;
        const int total = Kn * Fn * On;
        weff_kernel<<<(total + 255) / 256, 256, 0, stream>>>(W_eq, perms1, perms2, Weff);
        edge_kernel<true><<<Bn * En, 64, 0, stream>>>(
            sites1, sites2, bonds, Weff, b_eq, W_att, b_att,
            idx1, idx2, perms1, perms2, out);
    } else {
        edge_kernel<false><<<Bn * En, 64, 0, stream>>>(
            sites1, sites2, bonds, W_eq, b_eq, W_att, b_att,
            idx1, idx2, perms1, perms2, out);
    }
}

// Round 2
// 100.010 us; speedup vs baseline: 1.0351x; 1.0351x over previous
//
#include <hip/hip_runtime.h>
#include <math.h>

#define Bn   2
#define En   2048
#define N1n  96
#define Kn   32
#define CINn 64
#define CBn  32
#define On   64
#define Gn   4
#define Fn   160   // 2*CIN + CB
#define NEG  0.01f
#define NW   8          // waves per block
#define NT   (NW * 64)  // 512 threads

// ---------------------------------------------------------------------------
// One block per (b, k2) bucket. All edges with idx2[e]==k2 share the same
// effective weight slice Weff[k2] = 0.25 * sum_g w_g(k2) * W_eq[g] AND the
// same output row out[b,k2,:], so:
//   - Weff slice staged in LDS once per block (40 KB)
//   - edge list built in-block by scanning idx2 (8 KB)
//   - 8 waves each run whole edges: LDS matvec -> leakyrelu -> sigmoid gate,
//     accumulate att*lat in registers
//   - single exclusive store of the output row (no atomics, no memset;
//     empty buckets write zeros)
// ---------------------------------------------------------------------------
__global__ void __launch_bounds__(NT, 1)
fused_kernel(const float* __restrict__ sites1, const float* __restrict__ sites2,
             const float* __restrict__ bonds,  const float* __restrict__ W_eq,
             const float* __restrict__ b_eq,   const float* __restrict__ W_att,
             const float* __restrict__ b_att,  const int* __restrict__ idx1,
             const int* __restrict__ idx2,     const int* __restrict__ perms1,
             const int* __restrict__ perms2,   float* __restrict__ out) {
    __shared__ float Weff[Fn][On];   // 40960 B
    __shared__ float vbuf[NW][Fn];   //  5120 B
    __shared__ float red[NW][On];    //  2048 B
    __shared__ float s2[CINn];       //   256 B
    __shared__ float wgs[Gn];
    __shared__ int   elist[En];      //  8192 B
    __shared__ int   ecount;

    const int t  = threadIdx.x;
    const int bk = blockIdx.x;
    const int b  = bk >> 5;          // Kn = 32
    const int k2 = bk & (Kn - 1);

    // group weights w_g(k2) = [perms1[g, j] == k2] where perms2[g, j] == k2
    if (t < Gn) {
        int g = t, j = 0;
        for (; j < Kn; ++j) if (perms2[g * Kn + j] == k2) break;
        wgs[g] = (j < Kn && perms1[g * Kn + j] == k2) ? 1.f : 0.f;
    }
    if (t == Gn) ecount = 0;
    __syncthreads();

    // stage Weff[k2] into LDS (float4-wise, coalesced)
    {
        const float w0 = wgs[0], w1 = wgs[1], w2 = wgs[2], w3 = wgs[3];
        const float4* W4 = (const float4*)W_eq;
        float4* Wd = (float4*)&Weff[0][0];
        const int n4 = Fn * On / 4;  // 2560 float4 per group
        for (int i = t; i < n4; i += NT) {
            float4 a0 = W4[i], a1 = W4[n4 + i], a2 = W4[2 * n4 + i], a3 = W4[3 * n4 + i];
            float4 r;
            r.x = 0.25f * (w0 * a0.x + w1 * a1.x + w2 * a2.x + w3 * a3.x);
            r.y = 0.25f * (w0 * a0.y + w1 * a1.y + w2 * a2.y + w3 * a3.y);
            r.z = 0.25f * (w0 * a0.z + w1 * a1.z + w2 * a2.z + w3 * a3.z);
            r.w = 0.25f * (w0 * a0.w + w1 * a1.w + w2 * a2.w + w3 * a3.w);
            Wd[i] = r;
        }
    }

    // build this bucket's edge list
    for (int e = t; e < En; e += NT)
        if (idx2[e] == k2) { int p = atomicAdd(&ecount, 1); elist[p] = e; }

    // sites2 row is shared by every edge in the bucket
    if (t < CINn) s2[t] = sites2[(b * Kn + k2) * CINn + t];
    __syncthreads();

    const int w    = t >> 6;
    const int lane = t & 63;
    const int og   = lane & 15;   // output quad: o = 4*og .. 4*og+3
    const int fg   = lane >> 4;   // f stripe: f ≡ fg (mod 4)

    const float4 be4 = ((const float4*)b_eq)[og];
    const float4 wa  = ((const float4*)W_att)[og];
    const float  ba  = b_att[0];
    const int    ec  = ecount;

    float4 oacc = make_float4(0.f, 0.f, 0.f, 0.f);

    for (int i = w; i < ec; i += NW) {
        const int e  = elist[i];
        const int i1 = idx1[e];

        // stage v = [sites1[b,i1], sites2[b,k2], bonds[b,e]] into this wave's buffer
        vbuf[w][lane]        = sites1[(b * N1n + i1) * CINn + lane];
        vbuf[w][CINn + lane] = s2[lane];
        if (lane < CBn) vbuf[w][2 * CINn + lane] = bonds[(b * En + e) * CBn + lane];
        __builtin_amdgcn_wave_barrier();   // wave-lockstep; pin LDS write->read order

        float4 acc = make_float4(0.f, 0.f, 0.f, 0.f);
#pragma unroll
        for (int fi = 0; fi < Fn / 4; ++fi) {
            const int f = 4 * fi + fg;
            const float  vf = vbuf[w][f];
            const float4 wv = *(const float4*)&Weff[f][og * 4];
            acc.x += vf * wv.x; acc.y += vf * wv.y;
            acc.z += vf * wv.z; acc.w += vf * wv.w;
        }
        __builtin_amdgcn_wave_barrier();

        // reduce the 4 f stripes (lanes differing in bits 4,5)
#pragma unroll
        for (int m = 16; m <= 32; m <<= 1) {
            acc.x += __shfl_xor(acc.x, m);
            acc.y += __shfl_xor(acc.y, m);
            acc.z += __shfl_xor(acc.z, m);
            acc.w += __shfl_xor(acc.w, m);
        }

        float4 lat;
        lat.x = acc.x + be4.x; lat.x = lat.x > 0.f ? lat.x : NEG * lat.x;
        lat.y = acc.y + be4.y; lat.y = lat.y > 0.f ? lat.y : NEG * lat.y;
        lat.z = acc.z + be4.z; lat.z = lat.z > 0.f ? lat.z : NEG * lat.z;
        lat.w = acc.w + be4.w; lat.w = lat.w > 0.f ? lat.w : NEG * lat.w;

        // attention dot over o (og bits 0..3; each fg group holds a full copy)
        float part = lat.x * wa.x + lat.y * wa.y + lat.z * wa.z + lat.w * wa.w;
#pragma unroll
        for (int m = 1; m <= 8; m <<= 1) part += __shfl_xor(part, m);

        const float att = 1.f / (1.f + expf(-(part + ba)));
        oacc.x += att * lat.x;
        oacc.y += att * lat.y;
        oacc.z += att * lat.z;
        oacc.w += att * lat.w;
    }

    if (fg == 0) *(float4*)&red[w][og * 4] = oacc;
    __syncthreads();

    if (t < On) {
        float s = 0.f;
#pragma unroll
        for (int q = 0; q < NW; ++q) s += red[q][t];
        out[((size_t)b * Kn + k2) * On + t] = s;
    }
}

// ---------------------------------------------------------------------------
extern "C" void kernel_launch(void* const* d_in, const int* in_sizes, int n_in,
                              void* d_out, int out_size, void* d_ws, size_t ws_size,
                              hipStream_t stream) {
    const float* sites1 = (const float*)d_in[0];
    const float* sites2 = (const float*)d_in[1];
    const float* bonds  = (const float*)d_in[2];
    const float* W_eq   = (const float*)d_in[3];
    const float* b_eq   = (const float*)d_in[4];
    const float* W_att  = (const float*)d_in[5];
    const float* b_att  = (const float*)d_in[6];
    /* d_in[7] = idx2_oh (unused — reduced algebraically) */
    const int*   idx1   = (const int*)d_in[8];
    const int*   idx2   = (const int*)d_in[9];
    const int*   perms1 = (const int*)d_in[10];
    const int*   perms2 = (const int*)d_in[11];
    float* out = (float*)d_out;

    fused_kernel<<<Bn * Kn, NT, 0, stream>>>(
        sites1, sites2, bonds, W_eq, b_eq, W_att, b_att,
        idx1, idx2, perms1, perms2, out);
}

// Round 3
// 99.081 us; speedup vs baseline: 1.0448x; 1.0094x over previous
//
#include <hip/hip_runtime.h>
#include <math.h>

#define Bn   2
#define En   2048
#define N1n  96
#define Kn   32
#define CINn 64
#define CBn  32
#define On   64
#define Gn   4
#define Fn   160   // 2*CIN + CB
#define NEG  0.01f
#define NW   8          // waves per block
#define NT   (NW * 64)  // 512 threads
#define EB   8          // edges batched per wave per Weff sweep

// ---------------------------------------------------------------------------
// One block per (b, k2) bucket; all its edges share Weff[k2] AND out[b,k2,:].
// R2 changes vs R1:
//  * inner loop batches EB=8 edges per Weff sweep: each ds_read_b128 of a
//    Weff fragment feeds 32 fmacs instead of 4 (8x less LDS-pipe traffic)
//  * the sites2 half of the matvec (f in [64,128)) is bucket-shared: its
//    partial p2[o] is computed once per wave, not per edge (-40% edge work)
// Varying-f layout: vs row = [sites1 (64) | bonds (32)] = 96 entries;
//   vsidx < 64 -> f = vsidx, else f = vsidx + 64.
// ---------------------------------------------------------------------------
__global__ void __launch_bounds__(NT, 1)
fused_kernel(const float* __restrict__ sites1, const float* __restrict__ sites2,
             const float* __restrict__ bonds,  const float* __restrict__ W_eq,
             const float* __restrict__ b_eq,   const float* __restrict__ W_att,
             const float* __restrict__ b_att,  const int* __restrict__ idx1,
             const int* __restrict__ idx2,     const int* __restrict__ perms1,
             const int* __restrict__ perms2,   float* __restrict__ out) {
    __shared__ float Weff[Fn][On];       // 40960 B
    __shared__ float vs[NW][EB][96];     // 24576 B
    __shared__ float red[NW][On];        //  2048 B
    __shared__ float s2[CINn];           //   256 B
    __shared__ float wgs[Gn];
    __shared__ int   elist[En];          //  8192 B
    __shared__ int   ecount;

    const int t  = threadIdx.x;
    const int bk = blockIdx.x;
    const int b  = bk >> 5;              // Kn = 32
    const int k2 = bk & (Kn - 1);

    // group weights w_g(k2) = [perms1[g, j] == k2] where perms2[g, j] == k2
    if (t < Gn) {
        int g = t, j = 0;
        for (; j < Kn; ++j) if (perms2[g * Kn + j] == k2) break;
        wgs[g] = (j < Kn && perms1[g * Kn + j] == k2) ? 1.f : 0.f;
    }
    if (t == Gn) ecount = 0;
    __syncthreads();

    // stage Weff[k2] into LDS (float4-wise, coalesced; W_eq is L2-hot)
    {
        const float w0 = wgs[0], w1 = wgs[1], w2 = wgs[2], w3 = wgs[3];
        const float4* W4 = (const float4*)W_eq;
        float4* Wd = (float4*)&Weff[0][0];
        const int n4 = Fn * On / 4;      // 2560 float4 per group
        for (int i = t; i < n4; i += NT) {
            float4 a0 = W4[i], a1 = W4[n4 + i], a2 = W4[2 * n4 + i], a3 = W4[3 * n4 + i];
            float4 r;
            r.x = 0.25f * (w0 * a0.x + w1 * a1.x + w2 * a2.x + w3 * a3.x);
            r.y = 0.25f * (w0 * a0.y + w1 * a1.y + w2 * a2.y + w3 * a3.y);
            r.z = 0.25f * (w0 * a0.z + w1 * a1.z + w2 * a2.z + w3 * a3.z);
            r.w = 0.25f * (w0 * a0.w + w1 * a1.w + w2 * a2.w + w3 * a3.w);
            Wd[i] = r;
        }
    }

    // build this bucket's edge list
    for (int e = t; e < En; e += NT)
        if (idx2[e] == k2) { int p = atomicAdd(&ecount, 1); elist[p] = e; }

    // sites2 row (shared by every edge in the bucket)
    if (t < CINn) s2[t] = sites2[(b * Kn + k2) * CINn + t];
    __syncthreads();

    const int w    = t >> 6;
    const int lane = t & 63;
    const int og   = lane & 15;          // output quad: o = 4*og .. 4*og+3
    const int fg   = lane >> 4;          // f stripe: f ≡ fg (mod 4)
    const int ec   = ecount;

    const float4 be4 = ((const float4*)b_eq)[og];
    const float4 wa  = ((const float4*)W_att)[og];
    const float  ba  = b_att[0];

    // shared sites2 partial: p2 = sum_{f in [64,128)} s2[f-64] * Weff[f][4og..]
    float4 p2 = make_float4(0.f, 0.f, 0.f, 0.f);
#pragma unroll
    for (int fi = 0; fi < 16; ++fi) {
        const int f  = 64 + 4 * fi + fg;
        const float  vf = s2[4 * fi + fg];
        const float4 wv = *(const float4*)&Weff[f][og * 4];
        p2.x += vf * wv.x; p2.y += vf * wv.y;
        p2.z += vf * wv.z; p2.w += vf * wv.w;
    }

    float4 oacc = make_float4(0.f, 0.f, 0.f, 0.f);

    for (int base = w * EB; base < ec; base += NW * EB) {
        const int nb = (ec - base < EB) ? (ec - base) : EB;

        // stage this batch's varying v entries: [sites1 row | bonds row]
        __builtin_amdgcn_wave_barrier();
#pragma unroll
        for (int j = 0; j < EB; ++j) {
            const int jj = j < nb ? j : nb - 1;    // clamp: pads reuse a valid edge
            const int e  = elist[base + jj];
            const int i1 = idx1[e];
            vs[w][j][lane] = sites1[((b * N1n + i1) << 6) + lane];
            if (lane < CBn) vs[w][j][CINn + lane] = bonds[(b * En + e) * CBn + lane];
        }
        __builtin_amdgcn_wave_barrier();

        float4 acc[EB];
#pragma unroll
        for (int j = 0; j < EB; ++j) acc[j] = p2;

        // matvec over the 96 varying f's; each Weff b128 feeds all EB edges
#pragma unroll
        for (int fi = 0; fi < 24; ++fi) {
            const int vsidx = 4 * fi + fg;
            const int f     = vsidx < CINn ? vsidx : vsidx + CINn;  // skip s2 band
            const float4 wv = *(const float4*)&Weff[f][og * 4];
#pragma unroll
            for (int j = 0; j < EB; ++j) {
                const float vf = vs[w][j][vsidx];
                acc[j].x += vf * wv.x; acc[j].y += vf * wv.y;
                acc[j].z += vf * wv.z; acc[j].w += vf * wv.w;
            }
        }
        __builtin_amdgcn_wave_barrier();

        // per-edge epilogue
#pragma unroll
        for (int j = 0; j < EB; ++j) {
            float4 a = acc[j];
#pragma unroll
            for (int m = 16; m <= 32; m <<= 1) {     // reduce the 4 f stripes
                a.x += __shfl_xor(a.x, m);
                a.y += __shfl_xor(a.y, m);
                a.z += __shfl_xor(a.z, m);
                a.w += __shfl_xor(a.w, m);
            }
            float4 lat;
            lat.x = a.x + be4.x; lat.x = lat.x > 0.f ? lat.x : NEG * lat.x;
            lat.y = a.y + be4.y; lat.y = lat.y > 0.f ? lat.y : NEG * lat.y;
            lat.z = a.z + be4.z; lat.z = lat.z > 0.f ? lat.z : NEG * lat.z;
            lat.w = a.w + be4.w; lat.w = lat.w > 0.f ? lat.w : NEG * lat.w;

            float part = lat.x * wa.x + lat.y * wa.y + lat.z * wa.z + lat.w * wa.w;
#pragma unroll
            for (int m = 1; m <= 8; m <<= 1) part += __shfl_xor(part, m);

            float att = 1.f / (1.f + expf(-(part + ba)));
            att *= (j < nb) ? 1.f : 0.f;             // mask clamp-padded edges
            oacc.x += att * lat.x;
            oacc.y += att * lat.y;
            oacc.z += att * lat.z;
            oacc.w += att * lat.w;
        }
    }

    if (fg == 0) *(float4*)&red[w][og * 4] = oacc;
    __syncthreads();

    if (t < On) {
        float s = 0.f;
#pragma unroll
        for (int q = 0; q < NW; ++q) s += red[q][t];
        out[((size_t)b * Kn + k2) * On + t] = s;
    }
}

// ---------------------------------------------------------------------------
extern "C" void kernel_launch(void* const* d_in, const int* in_sizes, int n_in,
                              void* d_out, int out_size, void* d_ws, size_t ws_size,
                              hipStream_t stream) {
    const float* sites1 = (const float*)d_in[0];
    const float* sites2 = (const float*)d_in[1];
    const float* bonds  = (const float*)d_in[2];
    const float* W_eq   = (const float*)d_in[3];
    const float* b_eq   = (const float*)d_in[4];
    const float* W_att  = (const float*)d_in[5];
    const float* b_att  = (const float*)d_in[6];
    /* d_in[7] = idx2_oh (unused — reduced algebraically) */
    const int*   idx1   = (const int*)d_in[8];
    const int*   idx2   = (const int*)d_in[9];
    const int*   perms1 = (const int*)d_in[10];
    const int*   perms2 = (const int*)d_in[11];
    float* out = (float*)d_out;

    fused_kernel<<<Bn * Kn, NT, 0, stream>>>(
        sites1, sites2, bonds, W_eq, b_eq, W_att, b_att,
        idx1, idx2, perms1, perms2, out);
}